// Round 1
// baseline (616.659 us; speedup 1.0000x reference)
//
#include <hip/hip_runtime.h>

#define IN_SIZE 224
#define KER 5
#define IN_CH 16
#define OUT_CH 64
#define NH 220
#define NB_TILES (NH * NH)       // 48400
#define XCH (IN_SIZE * IN_SIZE)  // 50176
#define OUT_PLANE NB_TILES       // 48400
#define LR_OVER_NB ((float)(0.005 / 48400.0))
#define GAMMA_F 0.99f
#define ONE_MINUS_GAMMA 0.01f
#define EPS_F 0.01f

// ---------------- Kernel 1: 5x5 conv, LDS-tiled, 16x16 output tile ----------------
__global__ __launch_bounds__(256) void conv_kernel(const float* __restrict__ x,
                                                   const float* __restrict__ W,
                                                   float* __restrict__ out) {
    __shared__ float xs[IN_CH * 20 * 20];  // 25.6 KB
    __shared__ float wsm[IN_CH * 25];      // 1.6 KB

    const int oc = blockIdx.z;
    const int ti = blockIdx.y * 16;
    const int tj = blockIdx.x * 16;
    const int tx = threadIdx.x;
    const int ty = threadIdx.y;
    const int tid = ty * 16 + tx;

    // stage W[oc] (400 floats)
    for (int idx = tid; idx < IN_CH * 25; idx += 256) wsm[idx] = W[oc * 400 + idx];
    // stage x tile: 16 channels x 20x20
    for (int idx = tid; idx < IN_CH * 400; idx += 256) {
        int c = idx / 400;
        int rem = idx - c * 400;
        int r = rem / 20;
        int col = rem - r * 20;
        int gy = ti + r, gx = tj + col;
        float v = 0.f;
        if (gy < IN_SIZE && gx < IN_SIZE) v = x[c * XCH + gy * IN_SIZE + gx];
        xs[idx] = v;
    }
    __syncthreads();

    float acc = 0.f;
    for (int c = 0; c < IN_CH; c++) {
        const float* xc = &xs[c * 400];
        const float* wc = &wsm[c * 25];
#pragma unroll
        for (int ki = 0; ki < KER; ki++) {
#pragma unroll
            for (int kj = 0; kj < KER; kj++) {
                acc += wc[ki * 5 + kj] * xc[(ty + ki) * 20 + (tx + kj)];
            }
        }
    }
    int i = ti + ty, j = tj + tx;
    if (i < NH && j < NH) out[oc * OUT_PLANE + i * NH + j] = acc;
}

// ---------------- Kernel 2: inhibition (in-place on out) ----------------
__global__ __launch_bounds__(256) void inhibition_kernel(float* __restrict__ out) {
    int p = blockIdx.x * 256 + threadIdx.x;
    if (p >= NB_TILES) return;
    float m = 0.f;
#pragma unroll 8
    for (int oc = 0; oc < OUT_CH; oc++) {
        float v = out[oc * OUT_PLANE + p];
        v = fmaxf(v, 0.f);
        m = fmaxf(m, v);
    }
    float inv = 1.f / (m + 1e-9f);
#pragma unroll 8
    for (int oc = 0; oc < OUT_CH; oc++) {
        float v = fmaxf(out[oc * OUT_PLANE + p], 0.f) * inv;
        float v2 = v * v;
        float v4 = v2 * v2;
        out[oc * OUT_PLANE + p] = v4 * v;
    }
}

// ---------------- Kernel 3: per-channel column sums of y ----------------
__global__ __launch_bounds__(256) void colsum_kernel(const float* __restrict__ y,
                                                     float* __restrict__ colsum) {
    int oc = blockIdx.x;
    const float* row = y + oc * OUT_PLANE;
    float s = 0.f;
    for (int p = threadIdx.x; p < NB_TILES; p += 256) s += row[p];
    __shared__ float sm[4];
    for (int off = 32; off; off >>= 1) s += __shfl_down(s, off);
    int lane = threadIdx.x & 63, wv = threadIdx.x >> 6;
    if (lane == 0) sm[wv] = s;
    __syncthreads();
    if (threadIdx.x == 0) colsum[oc] = sm[0] + sm[1] + sm[2] + sm[3];
}

// ---------------- Kernel 4: yty[a][b] = sum_p y[a][p] * y[b][p] ----------------
__global__ __launch_bounds__(256) void yty_kernel(const float* __restrict__ y,
                                                  float* __restrict__ yty) {
    int a = blockIdx.x >> 6;
    int b = blockIdx.x & 63;
    const float* ya = y + a * OUT_PLANE;
    const float* yb = y + b * OUT_PLANE;
    float s = 0.f;
    for (int p = threadIdx.x; p < NB_TILES; p += 256) s += ya[p] * yb[p];
    __shared__ float sm[4];
    for (int off = 32; off; off >>= 1) s += __shfl_down(s, off);
    int lane = threadIdx.x & 63, wv = threadIdx.x >> 6;
    if (lane == 0) sm[wv] = s;
    __syncthreads();
    if (threadIdx.x == 0) yty[blockIdx.x] = sm[0] + sm[1] + sm[2] + sm[3];
}

// ---------------- Kernel 5: M[o][c*25+a] = sum_p y[o][p] * x[c][i+ki][j+kj] ----------------
__global__ __launch_bounds__(256) void ytxf_kernel(const float* __restrict__ y,
                                                   const float* __restrict__ x,
                                                   float* __restrict__ M) {
    int o = blockIdx.x >> 4;   // 0..63
    int c = blockIdx.x & 15;   // 0..15
    float acc[25];
#pragma unroll
    for (int a = 0; a < 25; a++) acc[a] = 0.f;

    const float* yo = y + o * OUT_PLANE;
    const float* xc = x + c * XCH;
    for (int p = threadIdx.x; p < NB_TILES; p += 256) {
        int i = p / NH;
        int j = p - i * NH;
        float yv = yo[p];
        const float* xp = xc + i * IN_SIZE + j;
#pragma unroll
        for (int ki = 0; ki < KER; ki++) {
#pragma unroll
            for (int kj = 0; kj < KER; kj++) {
                acc[ki * 5 + kj] = fmaf(yv, xp[ki * IN_SIZE + kj], acc[ki * 5 + kj]);
            }
        }
    }
    // block-reduce 25 accumulators
    __shared__ float sred[4 * 25];
    int lane = threadIdx.x & 63, wv = threadIdx.x >> 6;
#pragma unroll
    for (int a = 0; a < 25; a++) {
        float v = acc[a];
        for (int off = 32; off; off >>= 1) v += __shfl_down(v, off);
        if (lane == 0) sred[wv * 25 + a] = v;
    }
    __syncthreads();
    if (threadIdx.x < 25) {
        float v = sred[threadIdx.x] + sred[25 + threadIdx.x] + sred[50 + threadIdx.x] +
                  sred[75 + threadIdx.x];
        M[blockIdx.x * 25 + threadIdx.x] = v;  // = o*400 + c*25 + a
    }
}

// ---------------- Kernel 6: exp_new + gfp (one wave of 64) ----------------
__global__ void finalize_stats(const float* __restrict__ exp_avg,
                               const float* __restrict__ colsum,
                               float* __restrict__ exp_out, float* __restrict__ gfp) {
    int o = threadIdx.x;  // 0..63
    float e = GAMMA_F * exp_avg[o] + ONE_MINUS_GAMMA * (colsum[o] / (float)NB_TILES);
    float s = e;
    for (int off = 32; off; off >>= 1) s += __shfl_down(s, off);
    s = __shfl(s, 0);
    float A = e / (s / (float)OUT_CH);
    float gp = EPS_F * tanhf(-EPS_F * (A - 1.f)) + 1.f;
    exp_out[o] = e;
    gfp[o] = gp;
}

// ---------------- Kernel 7: Wfinal ----------------
__global__ __launch_bounds__(256) void finalize_w_kernel(const float* __restrict__ W,
                                                         const float* __restrict__ yty,
                                                         const float* __restrict__ M,
                                                         const float* __restrict__ gfp,
                                                         float* __restrict__ Wout) {
    int idx = blockIdx.x * 256 + threadIdx.x;  // 0..25599
    int o = idx / 400;
    int q = idx - o * 400;
    float dot = 0.f;
#pragma unroll 8
    for (int k = 0; k < OUT_CH; k++) dot = fmaf(yty[o * 64 + k], W[k * 400 + q], dot);
    float w = W[idx] + LR_OVER_NB * (M[idx] - dot);
    w = fmaxf(w, 0.f);
    float gp = gfp[o];
    float pos = (w > 0.f ? w : 0.f) * gp;
    float neg = (w < 0.f ? w : 0.f) / gp;
    Wout[idx] = pos + neg;
}

extern "C" void kernel_launch(void* const* d_in, const int* in_sizes, int n_in,
                              void* d_out, int out_size, void* d_ws, size_t ws_size,
                              hipStream_t stream) {
    const float* x = (const float*)d_in[0];        // (1,16,224,224)
    const float* W = (const float*)d_in[1];        // (64,16,5,5)
    const float* exp_avg = (const float*)d_in[2];  // (64,)
    float* out = (float*)d_out;                    // out | Wfinal | exp_new

    float* ws = (float*)d_ws;
    float* yty = ws;              // 4096
    float* M = ws + 4096;         // 25600
    float* colsum = ws + 29696;   // 64
    float* gfp = ws + 29760;      // 64

    float* Wout = out + OUT_CH * OUT_PLANE;            // +3097600
    float* expout = Wout + OUT_CH * IN_CH * KER * KER; // +25600

    conv_kernel<<<dim3(14, 14, 64), dim3(16, 16), 0, stream>>>(x, W, out);
    inhibition_kernel<<<(NB_TILES + 255) / 256, 256, 0, stream>>>(out);
    colsum_kernel<<<64, 256, 0, stream>>>(out, colsum);
    yty_kernel<<<4096, 256, 0, stream>>>(out, yty);
    ytxf_kernel<<<1024, 256, 0, stream>>>(out, x, M);
    finalize_stats<<<1, 64, 0, stream>>>(exp_avg, colsum, expout, gfp);
    finalize_w_kernel<<<100, 256, 0, stream>>>(W, yty, M, gfp, Wout);
}

// Round 2
// 255.340 us; speedup vs baseline: 2.4151x; 2.4151x over previous
//
#include <hip/hip_runtime.h>

#define IN_SIZE 224
#define KER 5
#define IN_CH 16
#define OUT_CH 64
#define NH 220
#define NB_TILES (NH * NH)       // 48400
#define XCH (IN_SIZE * IN_SIZE)  // 50176
#define OUT_PLANE NB_TILES
#define LR_OVER_NB ((float)(0.005 / 48400.0))
#define GAMMA_F 0.99f
#define ONE_MINUS_GAMMA 0.01f
#define EPS_F 0.01f

#define TS 64
#define XT 68  // TS + KER - 1

// ---------------- Kernel 1: conv, 64x64 tile, 4x4 micro-tile, 2 oc/block ----------------
__global__ __launch_bounds__(256) void conv_kernel(const float* __restrict__ x,
                                                   const float* __restrict__ W,
                                                   float* __restrict__ out) {
    __shared__ float xs[XT * XT];  // 18.5 KB
    const int tx = threadIdx.x & 15;
    const int ty = threadIdx.x >> 4;
    const int ti = blockIdx.y * TS;
    const int tj = blockIdx.x * TS;
    const int oc0 = blockIdx.z * 2;

    float acc0[16], acc1[16];
#pragma unroll
    for (int i = 0; i < 16; i++) { acc0[i] = 0.f; acc1[i] = 0.f; }

    const float* W0 = W + oc0 * 400;
    const float* W1 = W0 + 400;

    for (int c = 0; c < IN_CH; c++) {
        __syncthreads();  // protect xs from previous iteration's readers
        // stage one channel: 68 rows x 17 float4
        for (int s = threadIdx.x; s < XT * 17; s += 256) {
            int row = s / 17;
            int q = s - row * 17;
            int gy = ti + row, gx = tj + 4 * q;
            float4 v = make_float4(0.f, 0.f, 0.f, 0.f);
            if (gy < IN_SIZE && gx < IN_SIZE)
                v = *(const float4*)(x + c * XCH + gy * IN_SIZE + gx);
            *(float4*)(xs + row * XT + 4 * q) = v;
        }
        __syncthreads();

        // W for this channel: wave-uniform -> scalar loads
        float w0[25], w1[25];
#pragma unroll
        for (int q = 0; q < 25; q++) { w0[q] = W0[c * 25 + q]; w1[q] = W1[c * 25 + q]; }

#pragma unroll
        for (int rr = 0; rr < 8; rr++) {
            int row = 4 * ty + rr;
            float xr[8];
            ((float4*)xr)[0] = *(const float4*)(xs + row * XT + 4 * tx);
            ((float4*)xr)[1] = *(const float4*)(xs + row * XT + 4 * tx + 4);
#pragma unroll
            for (int dy = 0; dy < 4; dy++) {
                int ki = rr - dy;
                if (ki >= 0 && ki <= 4) {
#pragma unroll
                    for (int kj = 0; kj < 5; kj++) {
                        float wv0 = w0[ki * 5 + kj];
                        float wv1 = w1[ki * 5 + kj];
#pragma unroll
                        for (int dx = 0; dx < 4; dx++) {
                            acc0[dy * 4 + dx] = fmaf(wv0, xr[dx + kj], acc0[dy * 4 + dx]);
                            acc1[dy * 4 + dx] = fmaf(wv1, xr[dx + kj], acc1[dy * 4 + dx]);
                        }
                    }
                }
            }
        }
    }

    int gj = tj + 4 * tx;
    if (gj < NH) {
#pragma unroll
        for (int dy = 0; dy < 4; dy++) {
            int gi = ti + 4 * ty + dy;
            if (gi < NH) {
                *(float4*)(out + oc0 * OUT_PLANE + gi * NH + gj) =
                    make_float4(acc0[dy * 4], acc0[dy * 4 + 1], acc0[dy * 4 + 2], acc0[dy * 4 + 3]);
                *(float4*)(out + (oc0 + 1) * OUT_PLANE + gi * NH + gj) =
                    make_float4(acc1[dy * 4], acc1[dy * 4 + 1], acc1[dy * 4 + 2], acc1[dy * 4 + 3]);
            }
        }
    }
}

// ---------------- Kernel 2: fused inhibition + colsum + y^T y (split-K) ----------------
#define KP 192
#define YS_S 193  // padded stride: 193 % 32 == 1 -> 2-way max on gram reads
__global__ __launch_bounds__(256) void inhib_gram_kernel(float* __restrict__ out,
                                                         float* __restrict__ yty,
                                                         float* __restrict__ colsum) {
    __shared__ float ys[OUT_CH * YS_S];  // 49.4 KB
    const int tid = threadIdx.x;
    const int pbase = blockIdx.x * KP;

    if (tid < KP) {
        int p = pbase + tid;
        bool valid = p < NB_TILES;
        float m = 0.f;
#pragma unroll 8
        for (int oc = 0; oc < OUT_CH; oc++) {
            float v = valid ? out[oc * OUT_PLANE + p] : 0.f;
            v = fmaxf(v, 0.f);
            ys[oc * YS_S + tid] = v;
            m = fmaxf(m, v);
        }
        float inv = 1.f / (m + 1e-9f);
#pragma unroll 8
        for (int oc = 0; oc < OUT_CH; oc++) {
            float v = ys[oc * YS_S + tid] * inv;
            float v2 = v * v;
            float v4 = v2 * v2;
            v = v4 * v;
            ys[oc * YS_S + tid] = v;
            if (valid) out[oc * OUT_PLANE + p] = v;
        }
    }
    __syncthreads();

    // colsum: one value per oc (threads 0..63)
    if (tid < OUT_CH) {
        const float* r = ys + tid * YS_S;
        float s = 0.f;
        for (int k = 0; k < KP; k++) s += r[k];
        atomicAdd(colsum + tid, s);
    }

    // gram: each thread a 4x4 (a,b) tile
    const int ta = tid >> 4, tb = tid & 15;
    float acc[16];
#pragma unroll
    for (int i = 0; i < 16; i++) acc[i] = 0.f;
    const float* ra = ys + (4 * ta) * YS_S;
    const float* rb = ys + (4 * tb) * YS_S;
    for (int k = 0; k < KP; k++) {
        float a0 = ra[k], a1 = ra[YS_S + k], a2 = ra[2 * YS_S + k], a3 = ra[3 * YS_S + k];
        float b0 = rb[k], b1 = rb[YS_S + k], b2 = rb[2 * YS_S + k], b3 = rb[3 * YS_S + k];
        acc[0] = fmaf(a0, b0, acc[0]);  acc[1] = fmaf(a0, b1, acc[1]);
        acc[2] = fmaf(a0, b2, acc[2]);  acc[3] = fmaf(a0, b3, acc[3]);
        acc[4] = fmaf(a1, b0, acc[4]);  acc[5] = fmaf(a1, b1, acc[5]);
        acc[6] = fmaf(a1, b2, acc[6]);  acc[7] = fmaf(a1, b3, acc[7]);
        acc[8] = fmaf(a2, b0, acc[8]);  acc[9] = fmaf(a2, b1, acc[9]);
        acc[10] = fmaf(a2, b2, acc[10]); acc[11] = fmaf(a2, b3, acc[11]);
        acc[12] = fmaf(a3, b0, acc[12]); acc[13] = fmaf(a3, b1, acc[13]);
        acc[14] = fmaf(a3, b2, acc[14]); acc[15] = fmaf(a3, b3, acc[15]);
    }
#pragma unroll
    for (int i = 0; i < 16; i++) {
        int a = 4 * ta + (i >> 2), b = 4 * tb + (i & 3);
        atomicAdd(yty + a * OUT_CH + b, acc[i]);
    }
}

// ---------------- Kernel 3: y^T xf, 4 oc per block, float4 everywhere ----------------
__global__ __launch_bounds__(256) void ytxf_kernel(const float* __restrict__ y,
                                                   const float* __restrict__ x,
                                                   float* __restrict__ Mpart) {
    const int c = blockIdx.x;       // 0..15
    const int og = blockIdx.y * 4;  // 0,4,...,60
    const int half = blockIdx.z;    // 0..1
    const int row0 = half * 110;

    float acc[4][25];
#pragma unroll
    for (int t = 0; t < 4; t++)
#pragma unroll
        for (int q = 0; q < 25; q++) acc[t][q] = 0.f;

    const float* xc = x + c * XCH;
    for (int ch = threadIdx.x; ch < 110 * 55; ch += 256) {
        int ii = ch / 55;
        int j = 4 * (ch - ii * 55);
        int i = row0 + ii;
        int p = i * NH + j;
        float4 yv[4];
#pragma unroll
        for (int t = 0; t < 4; t++) yv[t] = *(const float4*)(y + (og + t) * OUT_PLANE + p);
        float xr[5][8];
#pragma unroll
        for (int ki = 0; ki < 5; ki++) {
            ((float4*)xr[ki])[0] = *(const float4*)(xc + (i + ki) * IN_SIZE + j);
            ((float4*)xr[ki])[1] = *(const float4*)(xc + (i + ki) * IN_SIZE + j + 4);
        }
#pragma unroll
        for (int t = 0; t < 4; t++) {
            float yv4[4] = {yv[t].x, yv[t].y, yv[t].z, yv[t].w};
#pragma unroll
            for (int ki = 0; ki < 5; ki++) {
#pragma unroll
                for (int kj = 0; kj < 5; kj++) {
                    float a = acc[t][ki * 5 + kj];
                    a = fmaf(yv4[0], xr[ki][kj], a);
                    a = fmaf(yv4[1], xr[ki][kj + 1], a);
                    a = fmaf(yv4[2], xr[ki][kj + 2], a);
                    a = fmaf(yv4[3], xr[ki][kj + 3], a);
                    acc[t][ki * 5 + kj] = a;
                }
            }
        }
    }

    // block-reduce 100 accumulators
    __shared__ float sred[4 * 100];
    const int lane = threadIdx.x & 63, wv = threadIdx.x >> 6;
#pragma unroll
    for (int t = 0; t < 4; t++) {
#pragma unroll
        for (int q = 0; q < 25; q++) {
            float v = acc[t][q];
            for (int off = 32; off; off >>= 1) v += __shfl_down(v, off);
            if (lane == 0) sred[wv * 100 + t * 25 + q] = v;
        }
    }
    __syncthreads();
    if (threadIdx.x < 100) {
        float v = sred[threadIdx.x] + sred[100 + threadIdx.x] + sred[200 + threadIdx.x] +
                  sred[300 + threadIdx.x];
        int t = threadIdx.x / 25, q = threadIdx.x - 25 * t;
        Mpart[half * 25600 + (og + t) * 400 + c * 25 + q] = v;
    }
}

// ---------------- Kernel 4: exp_new + gfp ----------------
__global__ void finalize_stats(const float* __restrict__ exp_avg,
                               const float* __restrict__ colsum,
                               float* __restrict__ exp_out, float* __restrict__ gfp) {
    int o = threadIdx.x;  // 0..63
    float e = GAMMA_F * exp_avg[o] + ONE_MINUS_GAMMA * (colsum[o] / (float)NB_TILES);
    float s = e;
    for (int off = 32; off; off >>= 1) s += __shfl_down(s, off);
    s = __shfl(s, 0);
    float A = e / (s / (float)OUT_CH);
    float gp = EPS_F * tanhf(-EPS_F * (A - 1.f)) + 1.f;
    exp_out[o] = e;
    gfp[o] = gp;
}

// ---------------- Kernel 5: Wfinal ----------------
__global__ __launch_bounds__(256) void finalize_w_kernel(const float* __restrict__ W,
                                                         const float* __restrict__ yty,
                                                         const float* __restrict__ Mpart,
                                                         const float* __restrict__ gfp,
                                                         float* __restrict__ Wout) {
    int idx = blockIdx.x * 256 + threadIdx.x;  // 0..25599
    int o = idx / 400;
    int q = idx - o * 400;
    float dot = 0.f;
#pragma unroll 8
    for (int k = 0; k < OUT_CH; k++) dot = fmaf(yty[o * 64 + k], W[k * 400 + q], dot);
    float M = Mpart[idx] + Mpart[25600 + idx];
    float w = W[idx] + LR_OVER_NB * (M - dot);
    w = fmaxf(w, 0.f);
    float gp = gfp[o];
    float pos = (w > 0.f ? w : 0.f) * gp;
    float neg = (w < 0.f ? w : 0.f) / gp;
    Wout[idx] = pos + neg;
}

extern "C" void kernel_launch(void* const* d_in, const int* in_sizes, int n_in,
                              void* d_out, int out_size, void* d_ws, size_t ws_size,
                              hipStream_t stream) {
    const float* x = (const float*)d_in[0];
    const float* W = (const float*)d_in[1];
    const float* exp_avg = (const float*)d_in[2];
    float* out = (float*)d_out;

    float* ws = (float*)d_ws;
    float* yty = ws;             // 4096
    float* colsum = ws + 4096;   // 64
    float* gfp = ws + 4160;      // 64
    float* Mpart = ws + 4224;    // 2 * 25600

    float* Wout = out + OUT_CH * OUT_PLANE;
    float* expout = Wout + OUT_CH * IN_CH * KER * KER;

    hipMemsetAsync(ws, 0, (4096 + 64) * sizeof(float), stream);  // yty + colsum

    conv_kernel<<<dim3(4, 4, 32), 256, 0, stream>>>(x, W, out);
    inhib_gram_kernel<<<(NB_TILES + KP - 1) / KP, 256, 0, stream>>>(out, yty, colsum);
    ytxf_kernel<<<dim3(16, 16, 2), 256, 0, stream>>>(out, x, Mpart);
    finalize_stats<<<1, 64, 0, stream>>>(exp_avg, colsum, expout, gfp);
    finalize_w_kernel<<<100, 256, 0, stream>>>(W, yty, Mpart, gfp, Wout);
}